// Round 6
// baseline (229.920 us; speedup 1.0000x reference)
//
#include <hip/hip_runtime.h>

// SimpleRNN fused kernel for MI355X (gfx950).  B=32768, T=28, I=28, H=128, C=10.
//
// Transposed recurrence D[h][b] = W * S^T (A=W resident in VGPRs, B=S^T from
// LDS, D rows pack to b64 writes of row-major S[b][h]).
// MFMA 16x16x32 bf16 layouts (m89/m91/m120):
//   A: A[m=lane&15][k=(lane>>4)*8+j]   B: B[k=(lane>>4)*8+j][n=lane&15]
//   D: D[(lane>>4)*4+reg][lane&15]
//
// R6: ZERO global loads in the step loop. R1-R5 were all ~95-107us because the
// compiler drains vmcnt(0) at every s_barrier -> the per-step scattered x load
// latency hit every wave every step and no prefetch depth could help. Fix:
// x is staged into LDS as ready-made bf16 B-fragments in 4 chunks of 7 steps
// (coalesced dwordx4 reads of contiguous row segments, issued one step before
// each of the 3 restage points). In-loop x = 4 ds_read_b64, no conversion.
//   Xbuf: [32 rows][228] bf16 (7 t * 32 k-padded + pad4; k=28..31 zeroed once).
// Keep proven pieces: 2m x 2n wave split (no spills, R3), S-exchange stride
// 132 + b64 pairs (0 conflicts, R1/R3/R5), bias as MFMA C-op, R4 scalar Pade
// tanh (best measured; R5 asm version regressed).
// Grid 1024 x 256 = 4 blocks/CU, LDS 31488 B/block (4x fits 126/160 KB).

#define T_STEPS 28
#define S_STRIDE 132
#define X_STRIDE 228
#define NSLOT 1568          // 32 rows * 49 dwordx4 slots per 7-step chunk

typedef __attribute__((ext_vector_type(4))) float f32x4;
typedef __attribute__((ext_vector_type(8))) short short8;

#define MFMA16 __builtin_amdgcn_mfma_f32_16x16x32_bf16

__device__ __forceinline__ unsigned pack2(float lo, float hi) {
#if __has_builtin(__builtin_amdgcn_cvt_pk_bf16_f32)
  auto p = __builtin_amdgcn_cvt_pk_bf16_f32(lo, hi);   // RNE pack, 1 inst
  return __builtin_bit_cast(unsigned, p);
#else
  // round-half-up (==RNE except exact-midpoints): add 0x8000, take high bytes.
  unsigned a = __builtin_bit_cast(unsigned, lo) + 0x8000u;
  unsigned b = __builtin_bit_cast(unsigned, hi) + 0x8000u;
  return __builtin_amdgcn_perm(b, a, 0x07060302u);     // {b.hi16, a.hi16}
#endif
}

__device__ __forceinline__ float bf2f(unsigned short s) {
  return __builtin_bit_cast(float, (unsigned)s << 16);
}

__device__ __forceinline__ short8 to_frag(f32x4 a, f32x4 b) {
  union { unsigned u[4]; short8 v; } r;
  r.u[0] = pack2(a[0], a[1]);
  r.u[1] = pack2(a[2], a[3]);
  r.u[2] = pack2(b[0], b[1]);
  r.u[3] = pack2(b[2], b[3]);
  return r.v;
}

__device__ __forceinline__ short8 load_frag64(const unsigned short* sp, int off) {
  // two b64 reads; measured conflict-free at stride 132 (R1/R3/R5)
  union { uint2 d[2]; short8 v; } r;
  r.d[0] = *(const uint2*)(sp + off);
  r.d[1] = *(const uint2*)(sp + off + 4);
  return r.v;
}

// R4's tanh (best measured): Pade(5,4), scalar fp32, 4 rcp, med3 clamp.
// Max abs err ~1.2e-3; den >= 945 -> finite everywhere.
__device__ __forceinline__ f32x4 tanh4(f32x4 z) {
  f32x4 x2 = z * z;
  f32x4 p = 945.0f + x2 * (105.0f + x2);
  f32x4 q = 945.0f + x2 * (420.0f + 15.0f * x2);
  f32x4 num = z * p;
  f32x4 r;
#pragma unroll
  for (int i = 0; i < 4; ++i) r[i] = __builtin_amdgcn_rcpf(q[i]);
  f32x4 t = num * r;
#pragma unroll
  for (int i = 0; i < 4; ++i) t[i] = __builtin_amdgcn_fmed3f(t[i], -1.0f, 1.0f);
  return t;
}

__global__ __launch_bounds__(256, 4) void rnn_fused(
    const float* __restrict__ x,  const float* __restrict__ Uw,
    const float* __restrict__ Ub, const float* __restrict__ Ww,
    const float* __restrict__ Wb, const float* __restrict__ Vw,
    const float* __restrict__ Vb, float* __restrict__ out) {
  __shared__ __align__(16) unsigned short Sbuf[2][32 * S_STRIDE];
  __shared__ __align__(16) unsigned short Xbuf[32 * X_STRIDE];

  const int tid  = threadIdx.x;
  const int w    = tid >> 6;
  const int lane = tid & 63;
  const int l15  = lane & 15;
  const int q    = lane >> 4;           // 0..3
  const int mrow = w * 32;              // h base for this wave (2 m-tiles)
  const int b0   = blockIdx.x * 32;

  const f32x4 zero4 = {0.f, 0.f, 0.f, 0.f};

  // ---- persistent register fragments (proven: no spills at VGPR<=128) ----
  short8 wfrag[2][4];   // [mt][kt]
  short8 ufrag[2];      // [mt], K=32 padded (k>=28 zeroed)
  f32x4  bias[2];       // Ub[h]+Wb[h] at D rows h = mrow + mt*16 + q*4 + r
#pragma unroll
  for (int mt = 0; mt < 2; ++mt) {
    const int h = mrow + mt * 16 + l15;
    const float* wp = Ww + h * 128 + q * 8;
#pragma unroll
    for (int kt = 0; kt < 4; ++kt) {
      wfrag[mt][kt] = to_frag(*(const f32x4*)wp, *(const f32x4*)(wp + 4));
      wp += 32;
    }
    const float* up = Uw + h * 28 + q * 8;
    f32x4 u0 = *(const f32x4*)up;
    f32x4 u1 = zero4;
    if (q < 3) u1 = *(const f32x4*)(up + 4);
    ufrag[mt] = to_frag(u0, u1);
    const int hb = mrow + mt * 16 + q * 4;
    bias[mt] = *(const f32x4*)(Wb + hb) + *(const f32x4*)(Ub + hb);
  }

  const float* xblk = x + (size_t)b0 * 784;

  // ---- x chunk staging (7 slots/thread; recompute slot math per site) ----
  // slot s: row = s/49, rem = s%49, tl = rem/7, g = rem%7
  //   global f32 elem: row*784 + c*196 + tl*28 + g*4   (16B aligned)
  //   LDS bf16 elem:   row*228 + tl*32 + g*4           (8B aligned)
  // chunk 0: load + pack + write + zero k-pad (zeros persist for all chunks)
  {
    f32x4 r[7];
#pragma unroll
    for (int k = 0; k < 7; ++k) {
      int s = tid + 256 * k;
      if (s < NSLOT) {
        int row = s / 49, rem = s - row * 49, tl = rem / 7, g = rem - tl * 7;
        r[k] = *(const f32x4*)(xblk + row * 784 + tl * 28 + g * 4);
      }
    }
#pragma unroll
    for (int k = 0; k < 7; ++k) {
      int s = tid + 256 * k;
      if (s < NSLOT) {
        int row = s / 49, rem = s - row * 49, tl = rem / 7, g = rem - tl * 7;
        uint2 d; d.x = pack2(r[k][0], r[k][1]); d.y = pack2(r[k][2], r[k][3]);
        *(uint2*)(Xbuf + row * X_STRIDE + tl * 32 + g * 4) = d;
        if (g == 0) {  // zero k=28..31 for this (row, tl) once
          uint2 zz; zz.x = 0u; zz.y = 0u;
          *(uint2*)(Xbuf + row * X_STRIDE + tl * 32 + 28) = zz;
        }
      }
    }
  }
  __syncthreads();

  int ro[2], xo[2];
#pragma unroll
  for (int nt = 0; nt < 2; ++nt) {
    ro[nt] = (nt * 16 + l15) * S_STRIDE;
    xo[nt] = (nt * 16 + l15) * X_STRIDE + q * 8;
  }

  f32x4 acc[2][2];   // [mt][nt]
  f32x4 rpf[7];      // restage prefetch regs (live one step, 3x per kernel)

  // ---- t = 0 (S=0: projection only), x frag straight from LDS ----
  {
    short8 xf0 = load_frag64(&Xbuf[0], xo[0]);
    short8 xf1 = load_frag64(&Xbuf[0], xo[1]);
    unsigned short* wp = &Sbuf[1][0];
#pragma unroll
    for (int mt = 0; mt < 2; ++mt) {
      f32x4 d0 = MFMA16(ufrag[mt], xf0, bias[mt], 0, 0, 0);
      f32x4 d1 = MFMA16(ufrag[mt], xf1, bias[mt], 0, 0, 0);
      f32x4 t0 = tanh4(d0), t1 = tanh4(d1);
      uint2 dd0; dd0.x = pack2(t0[0], t0[1]); dd0.y = pack2(t0[2], t0[3]);
      uint2 dd1; dd1.x = pack2(t1[0], t1[1]); dd1.y = pack2(t1[2], t1[3]);
      *(uint2*)(wp + ro[0] + mrow + mt * 16 + q * 4) = dd0;
      *(uint2*)(wp + ro[1] + mrow + mt * 16 + q * 4) = dd1;
    }
  }
  __syncthreads();

  // ---- t = 1 .. 27 : NO global loads except 3 covered chunk prefetches ----
  int tl = 0;
#pragma unroll 1
  for (int t = 1; t < T_STEPS; ++t) {
    if (t == 7 || t == 14 || t == 21) {
      // write the prefetched chunk (loads issued last step, drained at its
      // barrier with a full step of cover), then make it visible.
#pragma unroll
      for (int k = 0; k < 7; ++k) {
        int s = tid + 256 * k;
        if (s < NSLOT) {
          int row = s / 49, rem = s - row * 49, tll = rem / 7, g = rem - tll * 7;
          uint2 d; d.x = pack2(rpf[k][0], rpf[k][1]);
          d.y = pack2(rpf[k][2], rpf[k][3]);
          *(uint2*)(Xbuf + row * X_STRIDE + tll * 32 + g * 4) = d;
        }
      }
      __syncthreads();
      tl = 0;
    } else {
      ++tl;
    }

    // issue next chunk's coalesced loads one step ahead of its restage point
    if (t == 6 || t == 13 || t == 20) {
      const int c = (t + 1) / 7;   // 1, 2, 3
#pragma unroll
      for (int k = 0; k < 7; ++k) {
        int s = tid + 256 * k;
        if (s < NSLOT) {
          int row = s / 49, rem = s - row * 49, tll = rem / 7, g = rem - tll * 7;
          rpf[k] = *(const f32x4*)(xblk + row * 784 + c * 196 + tll * 28 + g * 4);
        }
      }
    }

    // x B-frags for this step: pure LDS, pre-converted, k-padded
    short8 xf0 = load_frag64(&Xbuf[0], xo[0] + tl * 32);
    short8 xf1 = load_frag64(&Xbuf[0], xo[1] + tl * 32);

    const unsigned short* sp = &Sbuf[t & 1][0];
    const unsigned short* spA = sp + ro[0] + q * 8;
    const unsigned short* spB = sp + ro[1] + q * 8;

    // kt = 0 with bias as C-operand
    short8 sA = load_frag64(spA, 0);
    short8 sB = load_frag64(spB, 0);
#pragma unroll
    for (int mt = 0; mt < 2; ++mt) {
      acc[mt][0] = MFMA16(wfrag[mt][0], sA, bias[mt], 0, 0, 0);
      acc[mt][1] = MFMA16(wfrag[mt][0], sB, bias[mt], 0, 0, 0);
    }
#pragma unroll
    for (int kt = 1; kt < 4; ++kt) {
      sA = load_frag64(spA, kt * 32);
      sB = load_frag64(spB, kt * 32);
#pragma unroll
      for (int mt = 0; mt < 2; ++mt) {
        acc[mt][0] = MFMA16(wfrag[mt][kt], sA, acc[mt][0], 0, 0, 0);
        acc[mt][1] = MFMA16(wfrag[mt][kt], sB, acc[mt][1], 0, 0, 0);
      }
    }
#pragma unroll
    for (int mt = 0; mt < 2; ++mt) {
      acc[mt][0] = MFMA16(ufrag[mt], xf0, acc[mt][0], 0, 0, 0);
      acc[mt][1] = MFMA16(ufrag[mt], xf1, acc[mt][1], 0, 0, 0);
    }

    unsigned short* wp = &Sbuf[(t + 1) & 1][0];
#pragma unroll
    for (int mt = 0; mt < 2; ++mt)
#pragma unroll
      for (int nt = 0; nt < 2; ++nt) {
        f32x4 th = tanh4(acc[mt][nt]);
        uint2 dd; dd.x = pack2(th[0], th[1]); dd.y = pack2(th[2], th[3]);
        *(uint2*)(wp + ro[nt] + mrow + mt * 16 + q * 4) = dd;
      }
    __syncthreads();
  }

  // ---- epilogue: out[b][c] = sum_h S[b][h]*Vw[c][h] + Vb[c] ----
  // Final S is in Sbuf[(27+1)&1] = Sbuf[0]. 32 rows x 10 cols per block.
  {
    const unsigned short* sf = &Sbuf[0][0];
    const int r  = tid >> 3;        // 0..31
    const int c0 = tid & 7;         // col c0; threads with c0<2 also do c0+8
    const float* v0 = Vw + c0 * 128;
    const float* v1 = Vw + ((c0 & 1) + 8) * 128;
    const unsigned short* srow = sf + r * S_STRIDE;
    float a0 = 0.f, a1 = 0.f;
#pragma unroll 8
    for (int h = 0; h < 128; ++h) {
      float s = bf2f(srow[h]);
      a0 += s * v0[h];
      a1 += s * v1[h];
    }
    float* op = out + (size_t)(b0 + r) * 10;
    op[c0] = a0 + Vb[c0];
    if (c0 < 2) op[c0 + 8] = a1 + Vb[(c0 & 1) + 8];
  }
}

extern "C" void kernel_launch(void* const* d_in, const int* in_sizes, int n_in,
                              void* d_out, int out_size, void* d_ws, size_t ws_size,
                              hipStream_t stream) {
  const float* x  = (const float*)d_in[0];
  const float* Uw = (const float*)d_in[1];
  const float* Ub = (const float*)d_in[2];
  const float* Ww = (const float*)d_in[3];
  const float* Wb = (const float*)d_in[4];
  const float* Vw = (const float*)d_in[5];
  const float* Vb = (const float*)d_in[6];
  rnn_fused<<<1024, 256, 0, stream>>>(x, Uw, Ub, Ww, Wb, Vw, Vb, (float*)d_out);
}

// Round 7
// 200.290 us; speedup vs baseline: 1.1479x; 1.1479x over previous
//
#include <hip/hip_runtime.h>

// SimpleRNN fused kernel for MI355X (gfx950).  B=32768, T=28, I=28, H=128, C=10.
//
// Transposed recurrence D[h][b] = W * S^T (A=W resident in VGPRs, B=S^T from
// LDS, D rows pack to b64 writes of row-major S[b][h]).
// MFMA 16x16x32 bf16 layouts (m89/m91/m120):
//   A: A[m=lane&15][k=(lane>>4)*8+j]   B: B[k=(lane>>4)*8+j][n=lane&15]
//   D: D[(lane>>4)*4+reg][lane&15]
//
// R7: ZERO global traffic in the step loop, spill-proof (R6's lesson: 28
// prefetch VGPRs on top of 48 persistent -> scratch spills, 58 MB writes).
// Whole x block staged ONCE in the prologue into LDS as bf16 k-padded
// B-fragments; no restages, no prefetch regs, no chunk math in-loop.
//   Block = 16 batch rows (grid 2048, 4 blocks/CU):
//     Xbuf[16][900] bf16 = 28.8 KB  (28 t * 32 k + pad4; k>=28 zeroed)
//     Sbuf[2][16][132] bf16 = 8.4 KB (stride 132: measured 0 conflicts R1/R3/R5)
//     total 37.2 KB -> 4 blocks/CU (149 KB of 160).
//   X_STRIDE=900: b64-offset residue 225 mod 32 == 1 == S_STRIDE's 33 mod 32,
//   i.e. the exact bank pattern measured conflict-free.
// Wave w: mrow = w*32 (2 m-tiles), single n-tile (16 rows). 10 MFMA/wave/step.
// Persistent regs: wfrag 32 + ufrag 8 + bias 8 = 48 (no spills in R3/R5 at
// this budget, launch_bounds(256,4) cap 128).
// Keep: bias-as-MFMA-C, R4 scalar Pade(5,4) tanh (best measured).

#define T_STEPS 28
#define S_STRIDE 132
#define X_STRIDE 900
#define XSLOTS 3136          // 16 rows * 784 f32 / 4 per dwordx4

typedef __attribute__((ext_vector_type(4))) float f32x4;
typedef __attribute__((ext_vector_type(8))) short short8;

#define MFMA16 __builtin_amdgcn_mfma_f32_16x16x32_bf16

__device__ __forceinline__ unsigned pack2(float lo, float hi) {
#if __has_builtin(__builtin_amdgcn_cvt_pk_bf16_f32)
  auto p = __builtin_amdgcn_cvt_pk_bf16_f32(lo, hi);   // RNE pack, 1 inst
  return __builtin_bit_cast(unsigned, p);
#else
  unsigned a = __builtin_bit_cast(unsigned, lo);
  a += 0x7FFFu + ((a >> 16) & 1u);
  unsigned b = __builtin_bit_cast(unsigned, hi);
  b += 0x7FFFu + ((b >> 16) & 1u);
  return (a >> 16) | (b & 0xFFFF0000u);
#endif
}

__device__ __forceinline__ float bf2f(unsigned short s) {
  return __builtin_bit_cast(float, (unsigned)s << 16);
}

__device__ __forceinline__ short8 to_frag(f32x4 a, f32x4 b) {
  union { unsigned u[4]; short8 v; } r;
  r.u[0] = pack2(a[0], a[1]);
  r.u[1] = pack2(a[2], a[3]);
  r.u[2] = pack2(b[0], b[1]);
  r.u[3] = pack2(b[2], b[3]);
  return r.v;
}

__device__ __forceinline__ short8 load_frag64(const unsigned short* sp, int off) {
  // two b64 reads; measured conflict-free at the stride-132-pattern (R1/R3/R5)
  union { uint2 d[2]; short8 v; } r;
  r.d[0] = *(const uint2*)(sp + off);
  r.d[1] = *(const uint2*)(sp + off + 4);
  return r.v;
}

// Pade(5,4) tanh, scalar fp32 (best measured, R4): max err ~1.2e-3, den>=945.
__device__ __forceinline__ f32x4 tanh4(f32x4 z) {
  f32x4 x2 = z * z;
  f32x4 p = 945.0f + x2 * (105.0f + x2);
  f32x4 q = 945.0f + x2 * (420.0f + 15.0f * x2);
  f32x4 num = z * p;
  f32x4 r;
#pragma unroll
  for (int i = 0; i < 4; ++i) r[i] = __builtin_amdgcn_rcpf(q[i]);
  f32x4 t = num * r;
#pragma unroll
  for (int i = 0; i < 4; ++i) t[i] = __builtin_amdgcn_fmed3f(t[i], -1.0f, 1.0f);
  return t;
}

__global__ __launch_bounds__(256, 4) void rnn_fused(
    const float* __restrict__ x,  const float* __restrict__ Uw,
    const float* __restrict__ Ub, const float* __restrict__ Ww,
    const float* __restrict__ Wb, const float* __restrict__ Vw,
    const float* __restrict__ Vb, float* __restrict__ out) {
  __shared__ __align__(16) unsigned short Sbuf[2][16 * S_STRIDE];
  __shared__ __align__(16) unsigned short Xbuf[16 * X_STRIDE];

  const int tid  = threadIdx.x;
  const int w    = tid >> 6;
  const int lane = tid & 63;
  const int l15  = lane & 15;
  const int q    = lane >> 4;           // 0..3
  const int mrow = w * 32;              // h base for this wave (2 m-tiles)
  const int b0   = blockIdx.x * 16;

  const f32x4 zero4 = {0.f, 0.f, 0.f, 0.f};
  const float* xblk = x + (size_t)b0 * 784;

  // ---- prologue A: stage the whole x block -> Xbuf (bf16, k-padded) ----
  // slot s (dwordx4 of f32): global flat offset s*4 (fully coalesced).
  // LDS: row=s/196, g=s%196, t=g/7, j=g%7 -> row*900 + t*32 + j*4.
  {
    f32x4 xr[13];
#pragma unroll
    for (int k = 0; k < 13; ++k) {
      int s = tid + 256 * k;
      if (s < XSLOTS) xr[k] = *(const f32x4*)(xblk + s * 4);
    }
#pragma unroll
    for (int k = 0; k < 13; ++k) {
      int s = tid + 256 * k;
      if (s < XSLOTS) {
        int row = s / 196, g = s - row * 196, tt = g / 7, j = g - tt * 7;
        uint2 d; d.x = pack2(xr[k][0], xr[k][1]); d.y = pack2(xr[k][2], xr[k][3]);
        *(uint2*)(Xbuf + row * X_STRIDE + tt * 32 + j * 4) = d;
        if (j == 0) {   // zero k=28..31 once per (row,t)
          uint2 zz; zz.x = 0u; zz.y = 0u;
          *(uint2*)(Xbuf + row * X_STRIDE + tt * 32 + 28) = zz;
        }
      }
    }
  }

  // ---- prologue B: persistent weight fragments (after staging regs die) ----
  short8 wfrag[2][4];   // [mt][kt]
  short8 ufrag[2];      // [mt], K=32 padded (k>=28 zeroed)
  f32x4  bias[2];       // Ub[h]+Wb[h] at D rows h = mrow + mt*16 + q*4 + r
#pragma unroll
  for (int mt = 0; mt < 2; ++mt) {
    const int h = mrow + mt * 16 + l15;
    const float* wp = Ww + h * 128 + q * 8;
#pragma unroll
    for (int kt = 0; kt < 4; ++kt) {
      wfrag[mt][kt] = to_frag(*(const f32x4*)wp, *(const f32x4*)(wp + 4));
      wp += 32;
    }
    const float* up = Uw + h * 28 + q * 8;
    f32x4 u0 = *(const f32x4*)up;
    f32x4 u1 = zero4;
    if (q < 3) u1 = *(const f32x4*)(up + 4);
    ufrag[mt] = to_frag(u0, u1);
    const int hb = mrow + mt * 16 + q * 4;
    bias[mt] = *(const f32x4*)(Wb + hb) + *(const f32x4*)(Ub + hb);
  }
  __syncthreads();   // Xbuf visible

  const int ro = l15 * S_STRIDE;                 // S row base (batch = l15)
  const int xo = l15 * X_STRIDE + q * 8;         // x frag base
  f32x4 acc[2];

  // ---- t = 0 (S=0: projection only) ----
  {
    short8 xf = load_frag64(&Xbuf[0], xo);
    unsigned short* wp = &Sbuf[1][0];
#pragma unroll
    for (int mt = 0; mt < 2; ++mt) {
      f32x4 d0 = MFMA16(ufrag[mt], xf, bias[mt], 0, 0, 0);
      f32x4 t0 = tanh4(d0);
      uint2 dd; dd.x = pack2(t0[0], t0[1]); dd.y = pack2(t0[2], t0[3]);
      *(uint2*)(wp + ro + mrow + mt * 16 + q * 4) = dd;
    }
  }
  __syncthreads();

  // ---- t = 1 .. 27 : pure LDS/MFMA/VALU, zero global ----
#pragma unroll 1
  for (int t = 1; t < T_STEPS; ++t) {
    short8 xf = load_frag64(&Xbuf[0], xo + t * 32);

    const unsigned short* sp = &Sbuf[t & 1][0] + ro + q * 8;

    // kt = 0 with bias as C-operand
    short8 sA = load_frag64(sp, 0);
#pragma unroll
    for (int mt = 0; mt < 2; ++mt)
      acc[mt] = MFMA16(wfrag[mt][0], sA, bias[mt], 0, 0, 0);
#pragma unroll
    for (int kt = 1; kt < 4; ++kt) {
      sA = load_frag64(sp, kt * 32);
#pragma unroll
      for (int mt = 0; mt < 2; ++mt)
        acc[mt] = MFMA16(wfrag[mt][kt], sA, acc[mt], 0, 0, 0);
    }
#pragma unroll
    for (int mt = 0; mt < 2; ++mt)
      acc[mt] = MFMA16(ufrag[mt], xf, acc[mt], 0, 0, 0);

    unsigned short* wp = &Sbuf[(t + 1) & 1][0];
#pragma unroll
    for (int mt = 0; mt < 2; ++mt) {
      f32x4 th = tanh4(acc[mt]);
      uint2 dd; dd.x = pack2(th[0], th[1]); dd.y = pack2(th[2], th[3]);
      *(uint2*)(wp + ro + mrow + mt * 16 + q * 4) = dd;
    }
    __syncthreads();
  }

  // ---- epilogue: out[b][c] = sum_h S[b][h]*Vw[c][h] + Vb[c] ----
  // Final S in Sbuf[0]. 16 rows x 10 cols per block.
  {
    const int r  = tid >> 4;        // 0..15
    const int c0 = tid & 15;        // 0..15; only c0<10 active
    if (c0 < 10) {
      const float* v0 = Vw + c0 * 128;
      const unsigned short* srow = &Sbuf[0][0] + r * S_STRIDE;
      float a0 = 0.f;
#pragma unroll 8
      for (int h = 0; h < 128; ++h) a0 += bf2f(srow[h]) * v0[h];
      out[(size_t)(b0 + r) * 10 + c0] = a0 + Vb[c0];
    }
  }
}

extern "C" void kernel_launch(void* const* d_in, const int* in_sizes, int n_in,
                              void* d_out, int out_size, void* d_ws, size_t ws_size,
                              hipStream_t stream) {
  const float* x  = (const float*)d_in[0];
  const float* Uw = (const float*)d_in[1];
  const float* Ub = (const float*)d_in[2];
  const float* Ww = (const float*)d_in[3];
  const float* Wb = (const float*)d_in[4];
  const float* Vw = (const float*)d_in[5];
  const float* Vb = (const float*)d_in[6];
  rnn_fused<<<2048, 256, 0, stream>>>(x, Uw, Ub, Ww, Wb, Vw, Vb, (float*)d_out);
}